// Round 4
// baseline (292.501 us; speedup 1.0000x reference)
//
#include <hip/hip_runtime.h>
#include <stdint.h>

#define EMBED 768
#define NTOK 4096
#define NHEAD 12
#define HD 64

typedef __attribute__((ext_vector_type(8))) short bf16x8;
typedef __attribute__((ext_vector_type(4))) float f32x4;
typedef __attribute__((ext_vector_type(16))) float f32x16;
typedef unsigned short ushort_t;

// 0.125 (1/sqrt(64)) * log2(e): fold score scale + exp->exp2 into Q
#define QSCALE 0.18033688011112042f

__device__ __forceinline__ unsigned short f2bf(float f) {
  union { float f; unsigned u; } c; c.f = f;
  unsigned u = c.u;
  u += 0x7fffu + ((u >> 16) & 1u);   // round-to-nearest-even
  return (unsigned short)(u >> 16);
}

__device__ __forceinline__ void gld16(const void* g, void* l) {
  __builtin_amdgcn_global_load_lds((const __attribute__((address_space(1))) void*)g,
                                   (__attribute__((address_space(3))) void*)l,
                                   16, 0, 0);
}

// ---------------- x (fp32) -> bf16, 8 elems/thread ----------------
__global__ void cvt_x_kernel(const float* __restrict__ x, ushort_t* __restrict__ xb) {
  size_t i = ((size_t)blockIdx.x * 256 + threadIdx.x) * 8;
  float4 a = *(const float4*)(x + i);
  float4 b = *(const float4*)(x + i + 4);
  uint4 p;
  p.x = (unsigned)f2bf(a.x) | ((unsigned)f2bf(a.y) << 16);
  p.y = (unsigned)f2bf(a.z) | ((unsigned)f2bf(a.w) << 16);
  p.z = (unsigned)f2bf(b.x) | ((unsigned)f2bf(b.y) << 16);
  p.w = (unsigned)f2bf(b.z) | ((unsigned)f2bf(b.w) << 16);
  *(uint4*)(xb + i) = p;
}

// ---------------- W [768][768] fp32 -> W^T [out][in] bf16, 4 matrices in one launch ----------------
__global__ void transpose_w4_kernel(const float* __restrict__ w0, const float* __restrict__ w1,
                                    const float* __restrict__ w2, const float* __restrict__ w3,
                                    ushort_t* __restrict__ d0, ushort_t* __restrict__ d1,
                                    ushort_t* __restrict__ d2, ushort_t* __restrict__ d3) {
  __shared__ float t[32][33];
  int z = blockIdx.z;
  const float* w = (z == 0) ? w0 : (z == 1) ? w1 : (z == 2) ? w2 : w3;
  ushort_t* wt   = (z == 0) ? d0 : (z == 1) ? d1 : (z == 2) ? d2 : d3;
  int bx = blockIdx.x * 32, by = blockIdx.y * 32;
  int tx = threadIdx.x, ty = threadIdx.y;
  #pragma unroll
  for (int i = 0; i < 32; i += 8)
    t[ty + i][tx] = w[(size_t)(by + ty + i) * EMBED + bx + tx];
  __syncthreads();
  #pragma unroll
  for (int i = 0; i < 32; i += 8)
    wt[(size_t)(bx + ty + i) * EMBED + by + tx] = f2bf(t[tx][ty + i]);
}

// ---------------- GEMM: C[M][N] = A[M][K] * Bt[N][K]^T + bias ----------------
template<int MODE>
__global__ __launch_bounds__(256)
void gemm_bt_kernel(const ushort_t* __restrict__ A, const ushort_t* __restrict__ Bt,
                    const float* __restrict__ b0, const float* __restrict__ b1,
                    const float* __restrict__ b2,
                    ushort_t* __restrict__ qo, ushort_t* __restrict__ ko,
                    ushort_t* __restrict__ vto, float* __restrict__ out) {
  __shared__ ushort_t As[128 * 32];
  __shared__ ushort_t Bs[128 * 32];
  const int K = EMBED;
  int tid = threadIdx.x, lane = tid & 63, wid = tid >> 6;
  int wy = wid >> 1, wx = wid & 1;
  int r0 = lane >> 4, cq = lane & 15;
  int brow = blockIdx.y * 128, bcol = blockIdx.x * 128;

  f32x4 acc[4][4] = {};

  for (int k0 = 0; k0 < K; k0 += 32) {
    #pragma unroll
    for (int c = 0; c < 2; ++c) {
      int chunk = wid * 2 + c;
      int eoff = chunk * 512;
      int le = eoff + lane * 8;
      int row = le >> 5, col = le & 31;
      gld16(A + (size_t)(brow + row) * K + k0 + col, As + eoff);
      gld16(Bt + (size_t)(bcol + row) * K + k0 + col, Bs + eoff);
    }
    __syncthreads();
    bf16x8 af[4], bfr[4];
    #pragma unroll
    for (int i = 0; i < 4; ++i)
      af[i] = *(const bf16x8*)(As + (wy * 64 + i * 16 + cq) * 32 + r0 * 8);
    #pragma unroll
    for (int i = 0; i < 4; ++i)
      bfr[i] = *(const bf16x8*)(Bs + (wx * 64 + i * 16 + cq) * 32 + r0 * 8);
    #pragma unroll
    for (int i = 0; i < 4; ++i)
      #pragma unroll
      for (int j = 0; j < 4; ++j)
        acc[i][j] = __builtin_amdgcn_mfma_f32_16x16x32_bf16(af[i], bfr[j], acc[i][j], 0, 0, 0);
    __syncthreads();
  }

  int sec = bcol / 768;
  int ncol0 = bcol - sec * 768;
  const float* bias = (sec == 0) ? b0 : (sec == 1) ? b1 : b2;
  #pragma unroll
  for (int i = 0; i < 4; ++i) {
    #pragma unroll
    for (int j = 0; j < 4; ++j) {
      #pragma unroll
      for (int jj = 0; jj < 4; ++jj) {
        int m = brow + wy * 64 + i * 16 + r0 * 4 + jj;
        int nn = ncol0 + wx * 64 + j * 16 + cq;
        float val = acc[i][j][jj] + bias[nn];
        if constexpr (MODE == 0) {
          int head = nn >> 6, dd = nn & 63;
          if (sec == 0)       qo[((size_t)head * NTOK + m) * HD + dd] = f2bf(val * QSCALE);
          else if (sec == 1)  ko[((size_t)head * NTOK + m) * HD + dd] = f2bf(val);
          else                vto[((size_t)head * HD + dd) * NTOK + m] = f2bf(val);
        } else {
          out[(size_t)m * EMBED + nn] = val;
        }
      }
    }
  }
}

// ---------------- flash attention ----------------
// q,k: [12][4096][64] bf16 (q pre-scaled by QSCALE), vt: [12][64][4096] bf16
// o: [4096][768] bf16.
// Block = 512 threads = 8 waves = 2 q-groups x 4 key-splits. Each wave owns
// 64 q-rows (2x32) and 1/4 of the keys (valid: no-max softmax partials add).
// The two q-group waves sharing a key-split share one double-buffered K/V
// tile set (qg0 stages K, qg1 stages V). __syncthreads() per iteration both
// drains own vmcnt (tile-t landed) and publishes it to the partner; next-tile
// prefetch is issued AFTER the sync so no write-after-read race.
__device__ __forceinline__ void stage_half(const ushort_t* kh, const ushort_t* vh,
                                           int kb, char* base, int srow, int sslot, int qg) {
  if (qg == 0) {
    const ushort_t* kg = kh + (size_t)kb * HD;
    #pragma unroll
    for (int i = 0; i < 8; ++i)
      gld16(kg + ((i * 8 + srow) * HD + sslot * 8), base + i * 1024);
  } else {
    const ushort_t* vg = vh + kb;
    char* vbuf = base + 8192;
    #pragma unroll
    for (int i = 0; i < 8; ++i)
      gld16(vg + ((size_t)(i * 8 + srow) * NTOK + sslot * 8), vbuf + i * 1024);
  }
}

__global__ __launch_bounds__(512, 2)
void flash_kernel(const ushort_t* __restrict__ q, const ushort_t* __restrict__ k,
                  const ushort_t* __restrict__ vt, ushort_t* __restrict__ o) {
  __shared__ __align__(16) char lds[131072];   // 4 key-splits x 2 bufs x (8KB K + 8KB V)
  const int tid = threadIdx.x;
  const int lane = tid & 63;
  const int wid = tid >> 6;
  const int qg = wid >> 2;               // q-group 0/1
  const int ks = wid & 3;                // key-split 0..3
  const int head = blockIdx.y;
  const int qbase = blockIdx.x * 128 + qg * 64;
  const int c31 = lane & 31;
  const int hi = lane >> 5;
  const int l7 = lane & 7;
  const int srow = lane >> 3;            // 0..7
  const int sslot = (lane & 7) ^ srow;   // pre-swizzled 16B slot in source row

  const ushort_t* qh = q + (size_t)head * NTOK * HD;
  const ushort_t* kh = k + (size_t)head * NTOK * HD;
  const ushort_t* vh = vt + (size_t)head * HD * NTOK;

  char* mybase = lds + ks * 32768;       // shared between the qg pair

  // Q B-frags (col = q-row = lane&31, k-elem = dc*16 + hi*8 + j)
  bf16x8 qf[2][4];
  #pragma unroll
  for (int qt = 0; qt < 2; ++qt)
    #pragma unroll
    for (int dc = 0; dc < 4; ++dc)
      qf[qt][dc] = *(const bf16x8*)(qh + (size_t)(qbase + qt * 32 + c31) * HD + dc * 16 + hi * 8);

  f32x16 oacc[2][2] = {};   // [ddt][qt], O^T partial: col=q, row=dd
  float lsum[2] = {0.f, 0.f};

  stage_half(kh, vh, ks * 64, mybase, srow, sslot, qg);

  #pragma unroll 2
  for (int it = 0; it < 16; ++it) {
    int cur = it & 1;
    __syncthreads();   // drains own vmcnt(0) (tile-it landed) + publishes to partner
    if (it < 15)
      stage_half(kh, vh, (ks + 4 * (it + 1)) * 64, mybase + (cur ^ 1) * 16384, srow, sslot, qg);
    const char* kbuf = mybase + cur * 16384;
    const char* vbuf = kbuf + 8192;

    // QK^T (swapped): s^T[key][q]; kf shared across both q-tiles
    f32x16 s[2][2] = {};   // [kt][qt]
    #pragma unroll
    for (int dc = 0; dc < 4; ++dc)
      #pragma unroll
      for (int kt = 0; kt < 2; ++kt) {
        bf16x8 kf = *(const bf16x8*)(kbuf + (kt * 32 + c31) * 128 + (((dc * 2 + hi) ^ l7) * 16));
        #pragma unroll
        for (int qt = 0; qt < 2; ++qt)
          s[kt][qt] = __builtin_amdgcn_mfma_f32_32x32x16_bf16(kf, qf[qt][dc], s[kt][qt], 0, 0, 0);
      }

    // softmax (no max: |s| bounded in base-2 domain) + in-register P build
    union pfu { unsigned u[4]; bf16x8 v; };
    pfu pf[2][4];
    #pragma unroll
    for (int qt = 0; qt < 2; ++qt) {
      unsigned w[2][8];
      #pragma unroll
      for (int kt = 0; kt < 2; ++kt) {
        float p[16];
        #pragma unroll
        for (int r = 0; r < 16; ++r)
          p[r] = __builtin_amdgcn_exp2f(s[kt][qt][r]);
        float s4[4];
        #pragma unroll
        for (int g = 0; g < 4; ++g)
          s4[g] = (p[4 * g] + p[4 * g + 1]) + (p[4 * g + 2] + p[4 * g + 3]);
        lsum[qt] += (s4[0] + s4[1]) + (s4[2] + s4[3]);
        #pragma unroll
        for (int m = 0; m < 8; ++m)
          asm("v_cvt_pk_bf16_f32 %0, %1, %2" : "=v"(w[kt][m]) : "v"(p[2 * m]), "v"(p[2 * m + 1]));
      }
      // build PV B-frags in-register via permlane32_swap (T12)
      #pragma unroll
      for (int kc = 0; kc < 4; ++kc) {
        int kt = kc >> 1, kl = kc & 1;
        #pragma unroll
        for (int e = 0; e < 2; ++e) {
          unsigned a = w[kt][e + 4 * kl];       // value needed by hi=0 targets
          unsigned b = w[kt][e + 4 * kl + 2];   // value needed by hi=1 targets
          asm("v_permlane32_swap_b32 %0, %1" : "+v"(a), "+v"(b));
          pf[qt][kc].u[e] = a;       // {a_lo, b_lo}
          pf[qt][kc].u[e + 2] = b;   // {a_hi, b_hi}
        }
      }
    }

    // PV (swapped): O^T[dd][q] += V^T[dd][key] * P^T[key][q]; vf shared across q-tiles
    #pragma unroll
    for (int kc = 0; kc < 4; ++kc)
      #pragma unroll
      for (int dt = 0; dt < 2; ++dt) {
        bf16x8 vf = *(const bf16x8*)(vbuf + (dt * 32 + c31) * 128 + (((kc * 2 + hi) ^ l7) * 16));
        #pragma unroll
        for (int qt = 0; qt < 2; ++qt)
          oacc[dt][qt] = __builtin_amdgcn_mfma_f32_32x32x16_bf16(vf, pf[qt][kc].v, oacc[dt][qt], 0, 0, 0);
      }
  }

  // ---- combine the 4 key-split waves per q-row via LDS f32 atomics ----
  __syncthreads();
  float* Oacc = (float*)lds;          // [128][68]
  float* lacc = Oacc + 128 * 68;      // [128]
  for (int t = tid; t < 128 * 68 + 128; t += 512)
    ((float*)lds)[t] = 0.f;
  __syncthreads();
  #pragma unroll
  for (int qt = 0; qt < 2; ++qt) {
    int qq = qg * 64 + qt * 32 + c31;
    atomicAdd(&lacc[qq], lsum[qt]);
    #pragma unroll
    for (int dt = 0; dt < 2; ++dt)
      #pragma unroll
      for (int g = 0; g < 4; ++g) {
        int dd = dt * 32 + 8 * g + 4 * hi;
        #pragma unroll
        for (int j = 0; j < 4; ++j)
          atomicAdd(&Oacc[qq * 68 + dd + j], oacc[dt][qt][4 * g + j]);
      }
  }
  __syncthreads();

  // write out: thread -> (q = tid>>2, 16 dd cols)
  int qq = tid >> 2, seg = tid & 3;
  float linv = 1.0f / lacc[qq];
  unsigned outw[8];
  #pragma unroll
  for (int m = 0; m < 8; ++m) {
    float lo = Oacc[qq * 68 + seg * 16 + 2 * m] * linv;
    float hh = Oacc[qq * 68 + seg * 16 + 2 * m + 1] * linv;
    asm("v_cvt_pk_bf16_f32 %0, %1, %2" : "=v"(outw[m]) : "v"(lo), "v"(hh));
  }
  ushort_t* op = o + (size_t)(blockIdx.x * 128 + qq) * EMBED + head * HD + seg * 16;
  uint4 u0; u0.x = outw[0]; u0.y = outw[1]; u0.z = outw[2]; u0.w = outw[3];
  uint4 u1; u1.x = outw[4]; u1.y = outw[5]; u1.z = outw[6]; u1.w = outw[7];
  *(uint4*)op = u0;
  *((uint4*)op + 1) = u1;
}

extern "C" void kernel_launch(void* const* d_in, const int* in_sizes, int n_in,
                              void* d_out, int out_size, void* d_ws, size_t ws_size,
                              hipStream_t stream) {
  const float* x  = (const float*)d_in[0];
  const float* Wq = (const float*)d_in[1];
  const float* bq = (const float*)d_in[2];
  const float* Wk = (const float*)d_in[3];
  const float* bk = (const float*)d_in[4];
  const float* Wv = (const float*)d_in[5];
  const float* bv = (const float*)d_in[6];
  const float* Wo = (const float*)d_in[7];
  const float* bo = (const float*)d_in[8];
  float* out = (float*)d_out;

  char* ws = (char*)d_ws;
  ushort_t* xb    = (ushort_t*)ws;  ws += (size_t)NTOK * EMBED * 2;
  ushort_t* wqkvt = (ushort_t*)ws;  ws += (size_t)3 * EMBED * EMBED * 2;
  ushort_t* wot   = (ushort_t*)ws;  ws += (size_t)EMBED * EMBED * 2;
  ushort_t* qb    = (ushort_t*)ws;  ws += (size_t)NTOK * EMBED * 2;
  ushort_t* kb2   = (ushort_t*)ws;  ws += (size_t)NTOK * EMBED * 2;
  ushort_t* vtb   = (ushort_t*)ws;  ws += (size_t)NTOK * EMBED * 2;
  ushort_t* ao    = (ushort_t*)ws;  ws += (size_t)NTOK * EMBED * 2;

  cvt_x_kernel<<<(NTOK * EMBED) / (256 * 8), 256, 0, stream>>>(x, xb);
  transpose_w4_kernel<<<dim3(24, 24, 4), dim3(32, 8), 0, stream>>>(
      Wq, Wk, Wv, Wo,
      wqkvt, wqkvt + (size_t)EMBED * EMBED, wqkvt + (size_t)2 * EMBED * EMBED, wot);

  gemm_bt_kernel<0><<<dim3(2304 / 128, NTOK / 128), 256, 0, stream>>>(
      xb, wqkvt, bq, bk, bv, qb, kb2, vtb, nullptr);

  flash_kernel<<<dim3(NTOK / 128, NHEAD), 512, 0, stream>>>(qb, kb2, vtb, ao);

  gemm_bt_kernel<1><<<dim3(EMBED / 128, NTOK / 128), 256, 0, stream>>>(
      ao, wot, bo, nullptr, nullptr, nullptr, nullptr, nullptr, out);
}

// Round 5
// 288.530 us; speedup vs baseline: 1.0138x; 1.0138x over previous
//
#include <hip/hip_runtime.h>
#include <stdint.h>

#define EMBED 768
#define NTOK 4096
#define NHEAD 12
#define HD 64

typedef __attribute__((ext_vector_type(8))) short bf16x8;
typedef __attribute__((ext_vector_type(4))) float f32x4;
typedef __attribute__((ext_vector_type(16))) float f32x16;
typedef unsigned short ushort_t;

// 0.125 (1/sqrt(64)) * log2(e): fold score scale + exp->exp2 into Q
#define QSCALE 0.18033688011112042f

__device__ __forceinline__ unsigned short f2bf(float f) {
  union { float f; unsigned u; } c; c.f = f;
  unsigned u = c.u;
  u += 0x7fffu + ((u >> 16) & 1u);   // round-to-nearest-even
  return (unsigned short)(u >> 16);
}

__device__ __forceinline__ void gld16(const void* g, void* l) {
  __builtin_amdgcn_global_load_lds((const __attribute__((address_space(1))) void*)g,
                                   (__attribute__((address_space(3))) void*)l,
                                   16, 0, 0);
}

// ---------------- x (fp32) -> bf16, 8 elems/thread ----------------
__global__ void cvt_x_kernel(const float* __restrict__ x, ushort_t* __restrict__ xb) {
  size_t i = ((size_t)blockIdx.x * 256 + threadIdx.x) * 8;
  float4 a = *(const float4*)(x + i);
  float4 b = *(const float4*)(x + i + 4);
  uint4 p;
  p.x = (unsigned)f2bf(a.x) | ((unsigned)f2bf(a.y) << 16);
  p.y = (unsigned)f2bf(a.z) | ((unsigned)f2bf(a.w) << 16);
  p.z = (unsigned)f2bf(b.x) | ((unsigned)f2bf(b.y) << 16);
  p.w = (unsigned)f2bf(b.z) | ((unsigned)f2bf(b.w) << 16);
  *(uint4*)(xb + i) = p;
}

// ---------------- W [768][768] fp32 -> W^T [out][in] bf16, 4 matrices in one launch ----------------
__global__ void transpose_w4_kernel(const float* __restrict__ w0, const float* __restrict__ w1,
                                    const float* __restrict__ w2, const float* __restrict__ w3,
                                    ushort_t* __restrict__ d0, ushort_t* __restrict__ d1,
                                    ushort_t* __restrict__ d2, ushort_t* __restrict__ d3) {
  __shared__ float t[32][33];
  int z = blockIdx.z;
  const float* w = (z == 0) ? w0 : (z == 1) ? w1 : (z == 2) ? w2 : w3;
  ushort_t* wt   = (z == 0) ? d0 : (z == 1) ? d1 : (z == 2) ? d2 : d3;
  int bx = blockIdx.x * 32, by = blockIdx.y * 32;
  int tx = threadIdx.x, ty = threadIdx.y;
  #pragma unroll
  for (int i = 0; i < 32; i += 8)
    t[ty + i][tx] = w[(size_t)(by + ty + i) * EMBED + bx + tx];
  __syncthreads();
  #pragma unroll
  for (int i = 0; i < 32; i += 8)
    wt[(size_t)(bx + ty + i) * EMBED + by + tx] = f2bf(t[tx][ty + i]);
}

// ---------------- GEMM: C[M][N] = A[M][K] * Bt[N][K]^T + bias ----------------
template<int MODE>
__global__ __launch_bounds__(256)
void gemm_bt_kernel(const ushort_t* __restrict__ A, const ushort_t* __restrict__ Bt,
                    const float* __restrict__ b0, const float* __restrict__ b1,
                    const float* __restrict__ b2,
                    ushort_t* __restrict__ qo, ushort_t* __restrict__ ko,
                    ushort_t* __restrict__ vto, float* __restrict__ out) {
  __shared__ ushort_t As[128 * 32];
  __shared__ ushort_t Bs[128 * 32];
  const int K = EMBED;
  int tid = threadIdx.x, lane = tid & 63, wid = tid >> 6;
  int wy = wid >> 1, wx = wid & 1;
  int r0 = lane >> 4, cq = lane & 15;
  int brow = blockIdx.y * 128, bcol = blockIdx.x * 128;

  f32x4 acc[4][4] = {};

  for (int k0 = 0; k0 < K; k0 += 32) {
    #pragma unroll
    for (int c = 0; c < 2; ++c) {
      int chunk = wid * 2 + c;
      int eoff = chunk * 512;
      int le = eoff + lane * 8;
      int row = le >> 5, col = le & 31;
      gld16(A + (size_t)(brow + row) * K + k0 + col, As + eoff);
      gld16(Bt + (size_t)(bcol + row) * K + k0 + col, Bs + eoff);
    }
    __syncthreads();
    bf16x8 af[4], bfr[4];
    #pragma unroll
    for (int i = 0; i < 4; ++i)
      af[i] = *(const bf16x8*)(As + (wy * 64 + i * 16 + cq) * 32 + r0 * 8);
    #pragma unroll
    for (int i = 0; i < 4; ++i)
      bfr[i] = *(const bf16x8*)(Bs + (wx * 64 + i * 16 + cq) * 32 + r0 * 8);
    #pragma unroll
    for (int i = 0; i < 4; ++i)
      #pragma unroll
      for (int j = 0; j < 4; ++j)
        acc[i][j] = __builtin_amdgcn_mfma_f32_16x16x32_bf16(af[i], bfr[j], acc[i][j], 0, 0, 0);
    __syncthreads();
  }

  int sec = bcol / 768;
  int ncol0 = bcol - sec * 768;
  const float* bias = (sec == 0) ? b0 : (sec == 1) ? b1 : b2;
  #pragma unroll
  for (int i = 0; i < 4; ++i) {
    #pragma unroll
    for (int j = 0; j < 4; ++j) {
      #pragma unroll
      for (int jj = 0; jj < 4; ++jj) {
        int m = brow + wy * 64 + i * 16 + r0 * 4 + jj;
        int nn = ncol0 + wx * 64 + j * 16 + cq;
        float val = acc[i][j][jj] + bias[nn];
        if constexpr (MODE == 0) {
          int head = nn >> 6, dd = nn & 63;
          if (sec == 0)       qo[((size_t)head * NTOK + m) * HD + dd] = f2bf(val * QSCALE);
          else if (sec == 1)  ko[((size_t)head * NTOK + m) * HD + dd] = f2bf(val);
          else                vto[((size_t)head * HD + dd) * NTOK + m] = f2bf(val);
        } else {
          out[(size_t)m * EMBED + nn] = val;
        }
      }
    }
  }
}

// ---------------- flash attention ----------------
// q,k: [12][4096][64] bf16 (q pre-scaled by QSCALE), vt: [12][64][4096] bf16
// o: [4096][768] bf16.
// Block = 4 waves (key-split x4), 64 q-rows per block. NO LDS in main loop:
// K/V fragments are loaded directly from global (L2-resident: K+V = 1MB/head),
// K prefetched one tile ahead in registers, V issued right after QK. Waves are
// fully independent (no barriers) -> 2 blocks/CU, 2 free-slipping waves/SIMD.
__global__ __launch_bounds__(256, 2)
void flash_kernel(const ushort_t* __restrict__ q, const ushort_t* __restrict__ k,
                  const ushort_t* __restrict__ vt, ushort_t* __restrict__ o) {
  __shared__ float cmb[64 * 68 + 64];   // 17.7 KB combine buffer (epilogue only)
  const int tid = threadIdx.x;
  const int lane = tid & 63;
  const int ks = tid >> 6;             // key-split 0..3
  const int head = blockIdx.y;
  const int qbase = blockIdx.x * 64;
  const int c31 = lane & 31;
  const int hi = lane >> 5;

  const ushort_t* qh = q + (size_t)head * NTOK * HD;
  const ushort_t* kh = k + (size_t)head * NTOK * HD;
  const ushort_t* vh = vt + (size_t)head * HD * NTOK;

  // Q B-frags (col = q-row = lane&31, k-elem = dc*16 + hi*8 + j)
  bf16x8 qf[2][4];
  #pragma unroll
  for (int qt = 0; qt < 2; ++qt)
    #pragma unroll
    for (int dc = 0; dc < 4; ++dc)
      qf[qt][dc] = *(const bf16x8*)(qh + (size_t)(qbase + qt * 32 + c31) * HD + dc * 16 + hi * 8);

  f32x16 oacc[2][2] = {};   // [ddt][qt], O^T partial: col=q, row=dd
  float lsum[2] = {0.f, 0.f};

  // preload K A-frags for tile 0: kfr[kt*4+dc] = K^T[key=kt*32+c31][dd=dc*16+hi*8 ..+7]
  bf16x8 kfr[8];
  {
    const ushort_t* kp = kh + (size_t)(ks * 64 + c31) * HD + hi * 8;
    #pragma unroll
    for (int kt = 0; kt < 2; ++kt)
      #pragma unroll
      for (int dc = 0; dc < 4; ++dc)
        kfr[kt * 4 + dc] = *(const bf16x8*)(kp + kt * 32 * HD + dc * 16);
  }

  for (int it = 0; it < 16; ++it) {
    const int kb = (ks + 4 * it) * 64;

    // QK^T (swapped): s^T[key][q]
    f32x16 s[2][2] = {};   // [kt][qt]
    __builtin_amdgcn_s_setprio(1);
    #pragma unroll
    for (int dc = 0; dc < 4; ++dc)
      #pragma unroll
      for (int kt = 0; kt < 2; ++kt)
        #pragma unroll
        for (int qt = 0; qt < 2; ++qt)
          s[kt][qt] = __builtin_amdgcn_mfma_f32_32x32x16_bf16(kfr[kt * 4 + dc], qf[qt][dc], s[kt][qt], 0, 0, 0);
    __builtin_amdgcn_s_setprio(0);

    // issue V A-frags for this tile (latency hidden under softmax)
    bf16x8 vfr[8];   // vfr[kc*2+dt] = V^T[dd=dt*32+c31][key=kb+kc*16+hi*8 ..+7]
    #pragma unroll
    for (int kc = 0; kc < 4; ++kc)
      #pragma unroll
      for (int dt = 0; dt < 2; ++dt)
        vfr[kc * 2 + dt] = *(const bf16x8*)(vh + (size_t)(dt * 32 + c31) * NTOK + kb + kc * 16 + hi * 8);

    // prefetch next tile's K frags (latency hidden under softmax+PV)
    if (it < 15) {
      const ushort_t* kp = kh + (size_t)((ks + 4 * (it + 1)) * 64 + c31) * HD + hi * 8;
      #pragma unroll
      for (int kt = 0; kt < 2; ++kt)
        #pragma unroll
        for (int dc = 0; dc < 4; ++dc)
          kfr[kt * 4 + dc] = *(const bf16x8*)(kp + kt * 32 * HD + dc * 16);
    }

    // softmax (no max: |s| bounded in base-2 domain) + in-register P build
    union pfu { unsigned u[4]; bf16x8 v; };
    pfu pf[2][4];
    #pragma unroll
    for (int qt = 0; qt < 2; ++qt) {
      unsigned w[2][8];
      #pragma unroll
      for (int kt = 0; kt < 2; ++kt) {
        float p[16];
        #pragma unroll
        for (int r = 0; r < 16; ++r)
          p[r] = __builtin_amdgcn_exp2f(s[kt][qt][r]);
        float s4[4];
        #pragma unroll
        for (int g = 0; g < 4; ++g)
          s4[g] = (p[4 * g] + p[4 * g + 1]) + (p[4 * g + 2] + p[4 * g + 3]);
        lsum[qt] += (s4[0] + s4[1]) + (s4[2] + s4[3]);
        #pragma unroll
        for (int m = 0; m < 8; ++m)
          asm("v_cvt_pk_bf16_f32 %0, %1, %2" : "=v"(w[kt][m]) : "v"(p[2 * m]), "v"(p[2 * m + 1]));
      }
      // build PV B-frags in-register via permlane32_swap (T12)
      #pragma unroll
      for (int kc = 0; kc < 4; ++kc) {
        int kt = kc >> 1, kl = kc & 1;
        #pragma unroll
        for (int e = 0; e < 2; ++e) {
          unsigned a = w[kt][e + 4 * kl];       // value needed by hi=0 targets
          unsigned b = w[kt][e + 4 * kl + 2];   // value needed by hi=1 targets
          asm("v_permlane32_swap_b32 %0, %1" : "+v"(a), "+v"(b));
          pf[qt][kc].u[e] = a;       // {a_lo, b_lo}
          pf[qt][kc].u[e + 2] = b;   // {a_hi, b_hi}
        }
      }
    }

    // PV (swapped): O^T[dd][q] += V^T[dd][key] * P^T[key][q]; vf shared across q-tiles
    __builtin_amdgcn_s_setprio(1);
    #pragma unroll
    for (int kc = 0; kc < 4; ++kc)
      #pragma unroll
      for (int dt = 0; dt < 2; ++dt)
        #pragma unroll
        for (int qt = 0; qt < 2; ++qt)
          oacc[dt][qt] = __builtin_amdgcn_mfma_f32_32x32x16_bf16(vfr[kc * 2 + dt], pf[qt][kc].v, oacc[dt][qt], 0, 0, 0);
    __builtin_amdgcn_s_setprio(0);
  }

  // ---- combine the 4 key-split waves per q-row via LDS f32 atomics ----
  float* Oacc = cmb;            // [64][68]
  float* lacc = cmb + 64 * 68;  // [64]
  for (int t = tid; t < 64 * 68 + 64; t += 256)
    cmb[t] = 0.f;
  __syncthreads();
  #pragma unroll
  for (int qt = 0; qt < 2; ++qt) {
    int qq = qt * 32 + c31;
    atomicAdd(&lacc[qq], lsum[qt]);
    #pragma unroll
    for (int dt = 0; dt < 2; ++dt)
      #pragma unroll
      for (int g = 0; g < 4; ++g) {
        int dd = dt * 32 + 8 * g + 4 * hi;
        #pragma unroll
        for (int j = 0; j < 4; ++j)
          atomicAdd(&Oacc[qq * 68 + dd + j], oacc[dt][qt][4 * g + j]);
      }
  }
  __syncthreads();

  // write out: thread -> (q = tid>>2, 16 dd cols)
  int qq = tid >> 2, seg = tid & 3;
  float linv = 1.0f / lacc[qq];
  unsigned outw[8];
  #pragma unroll
  for (int m = 0; m < 8; ++m) {
    float lo = Oacc[qq * 68 + seg * 16 + 2 * m] * linv;
    float hh = Oacc[qq * 68 + seg * 16 + 2 * m + 1] * linv;
    asm("v_cvt_pk_bf16_f32 %0, %1, %2" : "=v"(outw[m]) : "v"(lo), "v"(hh));
  }
  ushort_t* op = o + (size_t)(qbase + qq) * EMBED + head * HD + seg * 16;
  uint4 u0; u0.x = outw[0]; u0.y = outw[1]; u0.z = outw[2]; u0.w = outw[3];
  uint4 u1; u1.x = outw[4]; u1.y = outw[5]; u1.z = outw[6]; u1.w = outw[7];
  *(uint4*)op = u0;
  *((uint4*)op + 1) = u1;
}

extern "C" void kernel_launch(void* const* d_in, const int* in_sizes, int n_in,
                              void* d_out, int out_size, void* d_ws, size_t ws_size,
                              hipStream_t stream) {
  const float* x  = (const float*)d_in[0];
  const float* Wq = (const float*)d_in[1];
  const float* bq = (const float*)d_in[2];
  const float* Wk = (const float*)d_in[3];
  const float* bk = (const float*)d_in[4];
  const float* Wv = (const float*)d_in[5];
  const float* bv = (const float*)d_in[6];
  const float* Wo = (const float*)d_in[7];
  const float* bo = (const float*)d_in[8];
  float* out = (float*)d_out;

  char* ws = (char*)d_ws;
  ushort_t* xb    = (ushort_t*)ws;  ws += (size_t)NTOK * EMBED * 2;
  ushort_t* wqkvt = (ushort_t*)ws;  ws += (size_t)3 * EMBED * EMBED * 2;
  ushort_t* wot   = (ushort_t*)ws;  ws += (size_t)EMBED * EMBED * 2;
  ushort_t* qb    = (ushort_t*)ws;  ws += (size_t)NTOK * EMBED * 2;
  ushort_t* kb2   = (ushort_t*)ws;  ws += (size_t)NTOK * EMBED * 2;
  ushort_t* vtb   = (ushort_t*)ws;  ws += (size_t)NTOK * EMBED * 2;
  ushort_t* ao    = (ushort_t*)ws;  ws += (size_t)NTOK * EMBED * 2;

  cvt_x_kernel<<<(NTOK * EMBED) / (256 * 8), 256, 0, stream>>>(x, xb);
  transpose_w4_kernel<<<dim3(24, 24, 4), dim3(32, 8), 0, stream>>>(
      Wq, Wk, Wv, Wo,
      wqkvt, wqkvt + (size_t)EMBED * EMBED, wqkvt + (size_t)2 * EMBED * EMBED, wot);

  gemm_bt_kernel<0><<<dim3(2304 / 128, NTOK / 128), 256, 0, stream>>>(
      xb, wqkvt, bq, bk, bv, qb, kb2, vtb, nullptr);

  flash_kernel<<<dim3(NTOK / 64, NHEAD), 256, 0, stream>>>(qb, kb2, vtb, ao);

  gemm_bt_kernel<1><<<dim3(EMBED / 128, NTOK / 128), 256, 0, stream>>>(
      ao, wot, bo, nullptr, nullptr, nullptr, nullptr, nullptr, out);
}

// Round 6
// 265.024 us; speedup vs baseline: 1.1037x; 1.0887x over previous
//
#include <hip/hip_runtime.h>
#include <stdint.h>

#define EMBED 768
#define NTOK 4096
#define NHEAD 12
#define HD 64

typedef __attribute__((ext_vector_type(8))) short bf16x8;
typedef __attribute__((ext_vector_type(4))) float f32x4;
typedef __attribute__((ext_vector_type(16))) float f32x16;
typedef unsigned short ushort_t;

// 0.125 (1/sqrt(64)) * log2(e): fold score scale + exp->exp2 into Q
#define QSCALE 0.18033688011112042f

__device__ __forceinline__ unsigned short f2bf(float f) {
  union { float f; unsigned u; } c; c.f = f;
  unsigned u = c.u;
  u += 0x7fffu + ((u >> 16) & 1u);   // round-to-nearest-even
  return (unsigned short)(u >> 16);
}

__device__ __forceinline__ void gld16(const void* g, void* l) {
  __builtin_amdgcn_global_load_lds((const __attribute__((address_space(1))) void*)g,
                                   (__attribute__((address_space(3))) void*)l,
                                   16, 0, 0);
}

// ---------------- x (fp32) -> bf16, 8 elems/thread ----------------
__global__ void cvt_x_kernel(const float* __restrict__ x, ushort_t* __restrict__ xb) {
  size_t i = ((size_t)blockIdx.x * 256 + threadIdx.x) * 8;
  float4 a = *(const float4*)(x + i);
  float4 b = *(const float4*)(x + i + 4);
  uint4 p;
  p.x = (unsigned)f2bf(a.x) | ((unsigned)f2bf(a.y) << 16);
  p.y = (unsigned)f2bf(a.z) | ((unsigned)f2bf(a.w) << 16);
  p.z = (unsigned)f2bf(b.x) | ((unsigned)f2bf(b.y) << 16);
  p.w = (unsigned)f2bf(b.z) | ((unsigned)f2bf(b.w) << 16);
  *(uint4*)(xb + i) = p;
}

// ---------------- W [768][768] fp32 -> W^T [out][in] bf16, 4 matrices in one launch ----------------
__global__ void transpose_w4_kernel(const float* __restrict__ w0, const float* __restrict__ w1,
                                    const float* __restrict__ w2, const float* __restrict__ w3,
                                    ushort_t* __restrict__ d0, ushort_t* __restrict__ d1,
                                    ushort_t* __restrict__ d2, ushort_t* __restrict__ d3) {
  __shared__ float t[32][33];
  int z = blockIdx.z;
  const float* w = (z == 0) ? w0 : (z == 1) ? w1 : (z == 2) ? w2 : w3;
  ushort_t* wt   = (z == 0) ? d0 : (z == 1) ? d1 : (z == 2) ? d2 : d3;
  int bx = blockIdx.x * 32, by = blockIdx.y * 32;
  int tx = threadIdx.x, ty = threadIdx.y;
  #pragma unroll
  for (int i = 0; i < 32; i += 8)
    t[ty + i][tx] = w[(size_t)(by + ty + i) * EMBED + bx + tx];
  __syncthreads();
  #pragma unroll
  for (int i = 0; i < 32; i += 8)
    wt[(size_t)(bx + ty + i) * EMBED + by + tx] = f2bf(t[tx][ty + i]);
}

// ---------------- GEMM: C[M][N] = A[M][K] * Bt[N][K]^T + bias ----------------
template<int MODE>
__global__ __launch_bounds__(256)
void gemm_bt_kernel(const ushort_t* __restrict__ A, const ushort_t* __restrict__ Bt,
                    const float* __restrict__ b0, const float* __restrict__ b1,
                    const float* __restrict__ b2,
                    ushort_t* __restrict__ qo, ushort_t* __restrict__ ko,
                    ushort_t* __restrict__ vto, float* __restrict__ out) {
  __shared__ ushort_t As[128 * 32];
  __shared__ ushort_t Bs[128 * 32];
  const int K = EMBED;
  int tid = threadIdx.x, lane = tid & 63, wid = tid >> 6;
  int wy = wid >> 1, wx = wid & 1;
  int r0 = lane >> 4, cq = lane & 15;
  int brow = blockIdx.y * 128, bcol = blockIdx.x * 128;

  f32x4 acc[4][4] = {};

  for (int k0 = 0; k0 < K; k0 += 32) {
    #pragma unroll
    for (int c = 0; c < 2; ++c) {
      int chunk = wid * 2 + c;
      int eoff = chunk * 512;
      int le = eoff + lane * 8;
      int row = le >> 5, col = le & 31;
      gld16(A + (size_t)(brow + row) * K + k0 + col, As + eoff);
      gld16(Bt + (size_t)(bcol + row) * K + k0 + col, Bs + eoff);
    }
    __syncthreads();
    bf16x8 af[4], bfr[4];
    #pragma unroll
    for (int i = 0; i < 4; ++i)
      af[i] = *(const bf16x8*)(As + (wy * 64 + i * 16 + cq) * 32 + r0 * 8);
    #pragma unroll
    for (int i = 0; i < 4; ++i)
      bfr[i] = *(const bf16x8*)(Bs + (wx * 64 + i * 16 + cq) * 32 + r0 * 8);
    #pragma unroll
    for (int i = 0; i < 4; ++i)
      #pragma unroll
      for (int j = 0; j < 4; ++j)
        acc[i][j] = __builtin_amdgcn_mfma_f32_16x16x32_bf16(af[i], bfr[j], acc[i][j], 0, 0, 0);
    __syncthreads();
  }

  int sec = bcol / 768;
  int ncol0 = bcol - sec * 768;
  const float* bias = (sec == 0) ? b0 : (sec == 1) ? b1 : b2;
  #pragma unroll
  for (int i = 0; i < 4; ++i) {
    #pragma unroll
    for (int j = 0; j < 4; ++j) {
      #pragma unroll
      for (int jj = 0; jj < 4; ++jj) {
        int m = brow + wy * 64 + i * 16 + r0 * 4 + jj;
        int nn = ncol0 + wx * 64 + j * 16 + cq;
        float val = acc[i][j][jj] + bias[nn];
        if constexpr (MODE == 0) {
          int head = nn >> 6, dd = nn & 63;
          if (sec == 0)       qo[((size_t)head * NTOK + m) * HD + dd] = f2bf(val * QSCALE);
          else if (sec == 1)  ko[((size_t)head * NTOK + m) * HD + dd] = f2bf(val);
          else                vto[((size_t)head * HD + dd) * NTOK + m] = f2bf(val);
        } else {
          out[(size_t)m * EMBED + nn] = val;
        }
      }
    }
  }
}

// ---------------- flash attention ----------------
// q,k: [12][4096][64] bf16 (q pre-scaled by QSCALE), vt: [12][64][4096] bf16
// o: [4096][768] bf16.
// Block = 4 waves (key-split x4), 64 q-rows per block. KVBLK=32: each wave
// privately double-buffers a 4KB K tile [32][64] + 4KB V^T tile [64][32] via
// coalesced global_load_lds (pre-swizzled sources), counted vmcnt(8) waits,
// NO barriers in the main loop. 64KB LDS/block -> 2 blocks/CU -> 2 fully
// independent waves/SIMD covering each other's latencies.
__device__ __forceinline__ void stage32(const ushort_t* kh, const ushort_t* vh,
                                        int kb, char* buf, int lane) {
  // K tile: [32 keys][64 dd] bf16 rows of 128B (8 slots of 16B), slot ^= row&7
  const int srow = lane >> 3, l7 = lane & 7;
  const int ksl = l7 ^ srow;
  const ushort_t* kg = kh + (size_t)kb * HD;
  #pragma unroll
  for (int i = 0; i < 4; ++i)
    gld16(kg + ((i * 8 + srow) * HD + ksl * 8), buf + i * 1024);
  // V^T tile: [64 dd][32 keys] bf16 rows of 64B (4 slots of 16B), slot ^= row&3
  char* vbuf = buf + 4096;
  const int srw = lane >> 2;
  const int vsl = (lane & 3) ^ (srw & 3);
  const ushort_t* vg = vh + kb;
  #pragma unroll
  for (int i = 0; i < 4; ++i)
    gld16(vg + ((size_t)(i * 16 + srw) * NTOK + vsl * 8), vbuf + i * 1024);
}

__global__ __launch_bounds__(256, 2)
void flash_kernel(const ushort_t* __restrict__ q, const ushort_t* __restrict__ k,
                  const ushort_t* __restrict__ vt, ushort_t* __restrict__ o) {
  __shared__ __align__(16) char lds[65536];   // 4 waves x 2 bufs x (4KB K + 4KB V)
  const int tid = threadIdx.x;
  const int lane = tid & 63;
  const int ks = tid >> 6;             // key-split 0..3
  const int head = blockIdx.y;
  const int qbase = blockIdx.x * 64;
  const int c31 = lane & 31;
  const int hi = lane >> 5;

  const ushort_t* qh = q + (size_t)head * NTOK * HD;
  const ushort_t* kh = k + (size_t)head * NTOK * HD;
  const ushort_t* vh = vt + (size_t)head * HD * NTOK;

  char* mybase = lds + ks * 16384;     // wave-private

  // Q B-frags (col = q-row = lane&31, k-elem = dc*16 + hi*8 + j)
  bf16x8 qf[2][4];
  #pragma unroll
  for (int qt = 0; qt < 2; ++qt)
    #pragma unroll
    for (int dc = 0; dc < 4; ++dc)
      qf[qt][dc] = *(const bf16x8*)(qh + (size_t)(qbase + qt * 32 + c31) * HD + dc * 16 + hi * 8);

  f32x16 oacc[2][2] = {};   // [ddt][qt], O^T partial: col=q, row=dd
  float lsum[2] = {0.f, 0.f};

  stage32(kh, vh, ks * 32, mybase, lane);

  #pragma unroll 2
  for (int it = 0; it < 32; ++it) {
    const int cur = it & 1;
    if (it < 31) {
      stage32(kh, vh, (ks + 4 * (it + 1)) * 32, mybase + (cur ^ 1) * 8192, lane);
      asm volatile("s_waitcnt vmcnt(8)" ::: "memory");
    } else {
      asm volatile("s_waitcnt vmcnt(0)" ::: "memory");
    }
    const char* kbuf = mybase + cur * 8192;
    const char* vbuf = kbuf + 4096;

    // QK^T (swapped): s^T[key][q], 32 keys x 32 q per MFMA
    f32x16 s[2] = {};   // [qt]
    __builtin_amdgcn_s_setprio(1);
    #pragma unroll
    for (int dc = 0; dc < 4; ++dc) {
      bf16x8 kf = *(const bf16x8*)(kbuf + c31 * 128 + (((dc * 2 + hi) ^ (c31 & 7)) * 16));
      #pragma unroll
      for (int qt = 0; qt < 2; ++qt)
        s[qt] = __builtin_amdgcn_mfma_f32_32x32x16_bf16(kf, qf[qt][dc], s[qt], 0, 0, 0);
    }
    __builtin_amdgcn_s_setprio(0);

    // softmax (no max: |s| bounded in base-2 domain) + in-register P build
    union pfu { unsigned u[4]; bf16x8 v; };
    pfu pf[2][2];
    #pragma unroll
    for (int qt = 0; qt < 2; ++qt) {
      float p[16];
      #pragma unroll
      for (int r = 0; r < 16; ++r)
        p[r] = __builtin_amdgcn_exp2f(s[qt][r]);
      float s4[4];
      #pragma unroll
      for (int g = 0; g < 4; ++g)
        s4[g] = (p[4 * g] + p[4 * g + 1]) + (p[4 * g + 2] + p[4 * g + 3]);
      lsum[qt] += (s4[0] + s4[1]) + (s4[2] + s4[3]);
      unsigned w[8];
      #pragma unroll
      for (int m = 0; m < 8; ++m)
        asm("v_cvt_pk_bf16_f32 %0, %1, %2" : "=v"(w[m]) : "v"(p[2 * m]), "v"(p[2 * m + 1]));
      // build PV B-frags in-register via permlane32_swap (T12)
      #pragma unroll
      for (int kc = 0; kc < 2; ++kc) {
        #pragma unroll
        for (int e = 0; e < 2; ++e) {
          unsigned a = w[e + 4 * kc];       // value needed by hi=0 targets
          unsigned b = w[e + 4 * kc + 2];   // value needed by hi=1 targets
          asm("v_permlane32_swap_b32 %0, %1" : "+v"(a), "+v"(b));
          pf[qt][kc].u[e] = a;       // {a_lo, b_lo}
          pf[qt][kc].u[e + 2] = b;   // {a_hi, b_hi}
        }
      }
    }

    // PV (swapped): O^T[dd][q] += V^T[dd][key] * P^T[key][q]; vf shared across q-tiles
    __builtin_amdgcn_s_setprio(1);
    #pragma unroll
    for (int kc = 0; kc < 2; ++kc)
      #pragma unroll
      for (int dt = 0; dt < 2; ++dt) {
        bf16x8 vf = *(const bf16x8*)(vbuf + (dt * 32 + c31) * 64 + (((kc * 2 + hi) ^ (c31 & 3)) * 16));
        #pragma unroll
        for (int qt = 0; qt < 2; ++qt)
          oacc[dt][qt] = __builtin_amdgcn_mfma_f32_32x32x16_bf16(vf, pf[qt][kc].v, oacc[dt][qt], 0, 0, 0);
      }
    __builtin_amdgcn_s_setprio(0);
  }

  // ---- combine the 4 key-split waves per q-row via LDS f32 atomics ----
  __syncthreads();
  float* Oacc = (float*)lds;          // [64][68]
  float* lacc = Oacc + 64 * 68;       // [64]
  for (int t = tid; t < 64 * 68 + 64; t += 256)
    ((float*)lds)[t] = 0.f;
  __syncthreads();
  #pragma unroll
  for (int qt = 0; qt < 2; ++qt) {
    int qq = qt * 32 + c31;
    atomicAdd(&lacc[qq], lsum[qt]);
    #pragma unroll
    for (int dt = 0; dt < 2; ++dt)
      #pragma unroll
      for (int g = 0; g < 4; ++g) {
        int dd = dt * 32 + 8 * g + 4 * hi;
        #pragma unroll
        for (int j = 0; j < 4; ++j)
          atomicAdd(&Oacc[qq * 68 + dd + j], oacc[dt][qt][4 * g + j]);
      }
  }
  __syncthreads();

  // write out: thread -> (q = tid>>2, 16 dd cols)
  int qq = tid >> 2, seg = tid & 3;
  float linv = 1.0f / lacc[qq];
  unsigned outw[8];
  #pragma unroll
  for (int m = 0; m < 8; ++m) {
    float lo = Oacc[qq * 68 + seg * 16 + 2 * m] * linv;
    float hh = Oacc[qq * 68 + seg * 16 + 2 * m + 1] * linv;
    asm("v_cvt_pk_bf16_f32 %0, %1, %2" : "=v"(outw[m]) : "v"(lo), "v"(hh));
  }
  ushort_t* op = o + (size_t)(qbase + qq) * EMBED + head * HD + seg * 16;
  uint4 u0; u0.x = outw[0]; u0.y = outw[1]; u0.z = outw[2]; u0.w = outw[3];
  uint4 u1; u1.x = outw[4]; u1.y = outw[5]; u1.z = outw[6]; u1.w = outw[7];
  *(uint4*)op = u0;
  *((uint4*)op + 1) = u1;
}

extern "C" void kernel_launch(void* const* d_in, const int* in_sizes, int n_in,
                              void* d_out, int out_size, void* d_ws, size_t ws_size,
                              hipStream_t stream) {
  const float* x  = (const float*)d_in[0];
  const float* Wq = (const float*)d_in[1];
  const float* bq = (const float*)d_in[2];
  const float* Wk = (const float*)d_in[3];
  const float* bk = (const float*)d_in[4];
  const float* Wv = (const float*)d_in[5];
  const float* bv = (const float*)d_in[6];
  const float* Wo = (const float*)d_in[7];
  const float* bo = (const float*)d_in[8];
  float* out = (float*)d_out;

  char* ws = (char*)d_ws;
  ushort_t* xb    = (ushort_t*)ws;  ws += (size_t)NTOK * EMBED * 2;
  ushort_t* wqkvt = (ushort_t*)ws;  ws += (size_t)3 * EMBED * EMBED * 2;
  ushort_t* wot   = (ushort_t*)ws;  ws += (size_t)EMBED * EMBED * 2;
  ushort_t* qb    = (ushort_t*)ws;  ws += (size_t)NTOK * EMBED * 2;
  ushort_t* kb2   = (ushort_t*)ws;  ws += (size_t)NTOK * EMBED * 2;
  ushort_t* vtb   = (ushort_t*)ws;  ws += (size_t)NTOK * EMBED * 2;
  ushort_t* ao    = (ushort_t*)ws;  ws += (size_t)NTOK * EMBED * 2;

  cvt_x_kernel<<<(NTOK * EMBED) / (256 * 8), 256, 0, stream>>>(x, xb);
  transpose_w4_kernel<<<dim3(24, 24, 4), dim3(32, 8), 0, stream>>>(
      Wq, Wk, Wv, Wo,
      wqkvt, wqkvt + (size_t)EMBED * EMBED, wqkvt + (size_t)2 * EMBED * EMBED, wot);

  gemm_bt_kernel<0><<<dim3(2304 / 128, NTOK / 128), 256, 0, stream>>>(
      xb, wqkvt, bq, bk, bv, qb, kb2, vtb, nullptr);

  flash_kernel<<<dim3(NTOK / 64, NHEAD), 256, 0, stream>>>(qb, kb2, vtb, ao);

  gemm_bt_kernel<1><<<dim3(EMBED / 128, NTOK / 128), 256, 0, stream>>>(
      ao, wot, bo, nullptr, nullptr, nullptr, nullptr, nullptr, out);
}

// Round 7
// 260.392 us; speedup vs baseline: 1.1233x; 1.0178x over previous
//
#include <hip/hip_runtime.h>
#include <stdint.h>

#define EMBED 768
#define NTOK 4096
#define NHEAD 12
#define HD 64
#define VSTRIDE 4128   // 4096 + 32: breaks 8KB power-of-2 row stride (L2 channel spread)

typedef __attribute__((ext_vector_type(8))) short bf16x8;
typedef __attribute__((ext_vector_type(4))) float f32x4;
typedef __attribute__((ext_vector_type(16))) float f32x16;
typedef unsigned short ushort_t;

// 0.125 (1/sqrt(64)) * log2(e): fold score scale + exp->exp2 into Q
#define QSCALE 0.18033688011112042f

__device__ __forceinline__ unsigned short f2bf(float f) {
  union { float f; unsigned u; } c; c.f = f;
  unsigned u = c.u;
  u += 0x7fffu + ((u >> 16) & 1u);   // round-to-nearest-even
  return (unsigned short)(u >> 16);
}

__device__ __forceinline__ void gld16(const void* g, void* l) {
  __builtin_amdgcn_global_load_lds((const __attribute__((address_space(1))) void*)g,
                                   (__attribute__((address_space(3))) void*)l,
                                   16, 0, 0);
}

// ---------------- x (fp32) -> bf16, 8 elems/thread ----------------
__global__ void cvt_x_kernel(const float* __restrict__ x, ushort_t* __restrict__ xb) {
  size_t i = ((size_t)blockIdx.x * 256 + threadIdx.x) * 8;
  float4 a = *(const float4*)(x + i);
  float4 b = *(const float4*)(x + i + 4);
  uint4 p;
  p.x = (unsigned)f2bf(a.x) | ((unsigned)f2bf(a.y) << 16);
  p.y = (unsigned)f2bf(a.z) | ((unsigned)f2bf(a.w) << 16);
  p.z = (unsigned)f2bf(b.x) | ((unsigned)f2bf(b.y) << 16);
  p.w = (unsigned)f2bf(b.z) | ((unsigned)f2bf(b.w) << 16);
  *(uint4*)(xb + i) = p;
}

// ---------------- W [768][768] fp32 -> W^T [out][in] bf16, 4 matrices in one launch ----------------
__global__ void transpose_w4_kernel(const float* __restrict__ w0, const float* __restrict__ w1,
                                    const float* __restrict__ w2, const float* __restrict__ w3,
                                    ushort_t* __restrict__ d0, ushort_t* __restrict__ d1,
                                    ushort_t* __restrict__ d2, ushort_t* __restrict__ d3) {
  __shared__ float t[32][33];
  int z = blockIdx.z;
  const float* w = (z == 0) ? w0 : (z == 1) ? w1 : (z == 2) ? w2 : w3;
  ushort_t* wt   = (z == 0) ? d0 : (z == 1) ? d1 : (z == 2) ? d2 : d3;
  int bx = blockIdx.x * 32, by = blockIdx.y * 32;
  int tx = threadIdx.x, ty = threadIdx.y;
  #pragma unroll
  for (int i = 0; i < 32; i += 8)
    t[ty + i][tx] = w[(size_t)(by + ty + i) * EMBED + bx + tx];
  __syncthreads();
  #pragma unroll
  for (int i = 0; i < 32; i += 8)
    wt[(size_t)(bx + ty + i) * EMBED + by + tx] = f2bf(t[tx][ty + i]);
}

// ---------------- V [12][4096][64] bf16 -> V^T [12][64][VSTRIDE] bf16 ----------------
__global__ void transpose_v_kernel(const ushort_t* __restrict__ vb, ushort_t* __restrict__ vt) {
  __shared__ ushort_t t[32][33];
  int head = blockIdx.z;
  int bx = blockIdx.x * 32;   // dd base
  int by = blockIdx.y * 32;   // key base
  int tx = threadIdx.x, ty = threadIdx.y;
  const ushort_t* src = vb + (size_t)head * NTOK * HD;
  ushort_t* dst = vt + (size_t)head * HD * VSTRIDE;
  #pragma unroll
  for (int i = 0; i < 32; i += 8)
    t[ty + i][tx] = src[(size_t)(by + ty + i) * HD + bx + tx];
  __syncthreads();
  #pragma unroll
  for (int i = 0; i < 32; i += 8)
    dst[(size_t)(bx + ty + i) * VSTRIDE + by + tx] = t[tx][ty + i];
}

// ---------------- GEMM: C[M][N] = A[M][K] * Bt[N][K]^T + bias ----------------
// MODE 0: scatter epilogue into q (scaled), k, v (all row-major per head)
// MODE 1: fp32 out
template<int MODE>
__global__ __launch_bounds__(256)
void gemm_bt_kernel(const ushort_t* __restrict__ A, const ushort_t* __restrict__ Bt,
                    const float* __restrict__ b0, const float* __restrict__ b1,
                    const float* __restrict__ b2,
                    ushort_t* __restrict__ qo, ushort_t* __restrict__ ko,
                    ushort_t* __restrict__ vbo, float* __restrict__ out) {
  __shared__ ushort_t As[128 * 32];
  __shared__ ushort_t Bs[128 * 32];
  const int K = EMBED;
  int tid = threadIdx.x, lane = tid & 63, wid = tid >> 6;
  int wy = wid >> 1, wx = wid & 1;
  int r0 = lane >> 4, cq = lane & 15;
  int brow = blockIdx.y * 128, bcol = blockIdx.x * 128;

  f32x4 acc[4][4] = {};

  for (int k0 = 0; k0 < K; k0 += 32) {
    #pragma unroll
    for (int c = 0; c < 2; ++c) {
      int chunk = wid * 2 + c;
      int eoff = chunk * 512;
      int le = eoff + lane * 8;
      int row = le >> 5, col = le & 31;
      gld16(A + (size_t)(brow + row) * K + k0 + col, As + eoff);
      gld16(Bt + (size_t)(bcol + row) * K + k0 + col, Bs + eoff);
    }
    __syncthreads();
    bf16x8 af[4], bfr[4];
    #pragma unroll
    for (int i = 0; i < 4; ++i)
      af[i] = *(const bf16x8*)(As + (wy * 64 + i * 16 + cq) * 32 + r0 * 8);
    #pragma unroll
    for (int i = 0; i < 4; ++i)
      bfr[i] = *(const bf16x8*)(Bs + (wx * 64 + i * 16 + cq) * 32 + r0 * 8);
    #pragma unroll
    for (int i = 0; i < 4; ++i)
      #pragma unroll
      for (int j = 0; j < 4; ++j)
        acc[i][j] = __builtin_amdgcn_mfma_f32_16x16x32_bf16(af[i], bfr[j], acc[i][j], 0, 0, 0);
    __syncthreads();
  }

  int sec = bcol / 768;
  int ncol0 = bcol - sec * 768;
  const float* bias = (sec == 0) ? b0 : (sec == 1) ? b1 : b2;
  #pragma unroll
  for (int i = 0; i < 4; ++i) {
    #pragma unroll
    for (int j = 0; j < 4; ++j) {
      #pragma unroll
      for (int jj = 0; jj < 4; ++jj) {
        int m = brow + wy * 64 + i * 16 + r0 * 4 + jj;
        int nn = ncol0 + wx * 64 + j * 16 + cq;
        float val = acc[i][j][jj] + bias[nn];
        if constexpr (MODE == 0) {
          int head = nn >> 6, dd = nn & 63;
          if (sec == 0)       qo[((size_t)head * NTOK + m) * HD + dd] = f2bf(val * QSCALE);
          else if (sec == 1)  ko[((size_t)head * NTOK + m) * HD + dd] = f2bf(val);
          else                vbo[((size_t)head * NTOK + m) * HD + dd] = f2bf(val);
        } else {
          out[(size_t)m * EMBED + nn] = val;
        }
      }
    }
  }
}

// ---------------- flash attention ----------------
// q,k: [12][4096][64] bf16 (q pre-scaled), vt: [12][64][VSTRIDE] bf16.
// Block = 4 waves (key-split x4), 64 q-rows. Wave-private double-buffered
// 4KB K + 4KB V^T LDS tiles (coalesced global_load_lds, swizzled), counted
// vmcnt(8), no main-loop barriers. 64KB LDS -> 2 blocks/CU.
// XCD-affine mapping: b&7 = XCD (hw round-robin), each XCD gets a contiguous
// 96-slot range = <=2 heads -> K/V working set fits the 4MB per-XCD L2.
__device__ __forceinline__ void stage32(const ushort_t* kh, const ushort_t* vh,
                                        int kb, char* buf, int lane) {
  // K tile: [32 keys][64 dd] bf16 rows of 128B (8 slots of 16B), slot ^= row&7
  const int srow = lane >> 3, l7 = lane & 7;
  const int ksl = l7 ^ srow;
  const ushort_t* kg = kh + (size_t)kb * HD;
  #pragma unroll
  for (int i = 0; i < 4; ++i)
    gld16(kg + ((i * 8 + srow) * HD + ksl * 8), buf + i * 1024);
  // V^T tile: [64 dd][32 keys] bf16 rows of 64B (4 slots of 16B), slot ^= row&3
  char* vbuf = buf + 4096;
  const int srw = lane >> 2;
  const int vsl = (lane & 3) ^ (srw & 3);
  const ushort_t* vg = vh + kb;
  #pragma unroll
  for (int i = 0; i < 4; ++i)
    gld16(vg + ((size_t)(i * 16 + srw) * VSTRIDE + vsl * 8), vbuf + i * 1024);
}

__global__ __launch_bounds__(256, 2)
void flash_kernel(const ushort_t* __restrict__ q, const ushort_t* __restrict__ k,
                  const ushort_t* __restrict__ vt, ushort_t* __restrict__ o) {
  __shared__ __align__(16) char lds[65536];   // 4 waves x 2 bufs x (4KB K + 4KB V)
  const int tid = threadIdx.x;
  const int lane = tid & 63;
  const int ks = tid >> 6;             // key-split 0..3
  const int b = blockIdx.x;
  const int slot = (b & 7) * 96 + (b >> 3);   // XCD-affine: XCD owns 96 contiguous slots
  const int head = slot >> 6;
  const int qbase = (slot & 63) * 64;
  const int c31 = lane & 31;
  const int hi = lane >> 5;

  const ushort_t* qh = q + (size_t)head * NTOK * HD;
  const ushort_t* kh = k + (size_t)head * NTOK * HD;
  const ushort_t* vh = vt + (size_t)head * HD * VSTRIDE;

  char* mybase = lds + ks * 16384;     // wave-private

  // Q B-frags (col = q-row = lane&31, k-elem = dc*16 + hi*8 + j)
  bf16x8 qf[2][4];
  #pragma unroll
  for (int qt = 0; qt < 2; ++qt)
    #pragma unroll
    for (int dc = 0; dc < 4; ++dc)
      qf[qt][dc] = *(const bf16x8*)(qh + (size_t)(qbase + qt * 32 + c31) * HD + dc * 16 + hi * 8);

  f32x16 oacc[2][2] = {};   // [ddt][qt], O^T partial: col=q, row=dd
  float lsum[2] = {0.f, 0.f};

  stage32(kh, vh, ks * 32, mybase, lane);

  #pragma unroll 2
  for (int it = 0; it < 32; ++it) {
    const int cur = it & 1;
    if (it < 31) {
      stage32(kh, vh, (ks + 4 * (it + 1)) * 32, mybase + (cur ^ 1) * 8192, lane);
      asm volatile("s_waitcnt vmcnt(8)" ::: "memory");
    } else {
      asm volatile("s_waitcnt vmcnt(0)" ::: "memory");
    }
    const char* kbuf = mybase + cur * 8192;
    const char* vbuf = kbuf + 4096;

    // QK^T (swapped): s^T[key][q], 32 keys x 32 q per MFMA
    f32x16 s[2] = {};   // [qt]
    __builtin_amdgcn_s_setprio(1);
    #pragma unroll
    for (int dc = 0; dc < 4; ++dc) {
      bf16x8 kf = *(const bf16x8*)(kbuf + c31 * 128 + (((dc * 2 + hi) ^ (c31 & 7)) * 16));
      #pragma unroll
      for (int qt = 0; qt < 2; ++qt)
        s[qt] = __builtin_amdgcn_mfma_f32_32x32x16_bf16(kf, qf[qt][dc], s[qt], 0, 0, 0);
    }
    __builtin_amdgcn_s_setprio(0);

    // softmax (no max: |s| bounded in base-2 domain) + in-register P build
    union pfu { unsigned u[4]; bf16x8 v; };
    pfu pf[2][2];
    #pragma unroll
    for (int qt = 0; qt < 2; ++qt) {
      float p[16];
      #pragma unroll
      for (int r = 0; r < 16; ++r)
        p[r] = __builtin_amdgcn_exp2f(s[qt][r]);
      float s4[4];
      #pragma unroll
      for (int g = 0; g < 4; ++g)
        s4[g] = (p[4 * g] + p[4 * g + 1]) + (p[4 * g + 2] + p[4 * g + 3]);
      lsum[qt] += (s4[0] + s4[1]) + (s4[2] + s4[3]);
      unsigned w[8];
      #pragma unroll
      for (int m = 0; m < 8; ++m)
        asm("v_cvt_pk_bf16_f32 %0, %1, %2" : "=v"(w[m]) : "v"(p[2 * m]), "v"(p[2 * m + 1]));
      // build PV B-frags in-register via permlane32_swap (T12)
      #pragma unroll
      for (int kc = 0; kc < 2; ++kc) {
        #pragma unroll
        for (int e = 0; e < 2; ++e) {
          unsigned a = w[e + 4 * kc];       // value needed by hi=0 targets
          unsigned b2 = w[e + 4 * kc + 2];  // value needed by hi=1 targets
          asm("v_permlane32_swap_b32 %0, %1" : "+v"(a), "+v"(b2));
          pf[qt][kc].u[e] = a;       // {a_lo, b_lo}
          pf[qt][kc].u[e + 2] = b2;  // {a_hi, b_hi}
        }
      }
    }

    // PV (swapped): O^T[dd][q] += V^T[dd][key] * P^T[key][q]; vf shared across q-tiles
    __builtin_amdgcn_s_setprio(1);
    #pragma unroll
    for (int kc = 0; kc < 2; ++kc)
      #pragma unroll
      for (int dt = 0; dt < 2; ++dt) {
        bf16x8 vf = *(const bf16x8*)(vbuf + (dt * 32 + c31) * 64 + (((kc * 2 + hi) ^ (c31 & 3)) * 16));
        #pragma unroll
        for (int qt = 0; qt < 2; ++qt)
          oacc[dt][qt] = __builtin_amdgcn_mfma_f32_32x32x16_bf16(vf, pf[qt][kc].v, oacc[dt][qt], 0, 0, 0);
      }
    __builtin_amdgcn_s_setprio(0);
  }

  // ---- combine the 4 key-split waves per q-row via LDS f32 atomics ----
  __syncthreads();
  float* Oacc = (float*)lds;          // [64][68]
  float* lacc = Oacc + 64 * 68;       // [64]
  for (int t = tid; t < 64 * 68 + 64; t += 256)
    ((float*)lds)[t] = 0.f;
  __syncthreads();
  #pragma unroll
  for (int qt = 0; qt < 2; ++qt) {
    int qq = qt * 32 + c31;
    atomicAdd(&lacc[qq], lsum[qt]);
    #pragma unroll
    for (int dt = 0; dt < 2; ++dt)
      #pragma unroll
      for (int g = 0; g < 4; ++g) {
        int dd = dt * 32 + 8 * g + 4 * hi;
        #pragma unroll
        for (int j = 0; j < 4; ++j)
          atomicAdd(&Oacc[qq * 68 + dd + j], oacc[dt][qt][4 * g + j]);
      }
  }
  __syncthreads();

  // write out: thread -> (q = tid>>2, 16 dd cols)
  int qq = tid >> 2, seg = tid & 3;
  float linv = 1.0f / lacc[qq];
  unsigned outw[8];
  #pragma unroll
  for (int m = 0; m < 8; ++m) {
    float lo = Oacc[qq * 68 + seg * 16 + 2 * m] * linv;
    float hh = Oacc[qq * 68 + seg * 16 + 2 * m + 1] * linv;
    asm("v_cvt_pk_bf16_f32 %0, %1, %2" : "=v"(outw[m]) : "v"(lo), "v"(hh));
  }
  ushort_t* op = o + (size_t)(qbase + qq) * EMBED + head * HD + seg * 16;
  uint4 u0; u0.x = outw[0]; u0.y = outw[1]; u0.z = outw[2]; u0.w = outw[3];
  uint4 u1; u1.x = outw[4]; u1.y = outw[5]; u1.z = outw[6]; u1.w = outw[7];
  *(uint4*)op = u0;
  *((uint4*)op + 1) = u1;
}

extern "C" void kernel_launch(void* const* d_in, const int* in_sizes, int n_in,
                              void* d_out, int out_size, void* d_ws, size_t ws_size,
                              hipStream_t stream) {
  const float* x  = (const float*)d_in[0];
  const float* Wq = (const float*)d_in[1];
  const float* bq = (const float*)d_in[2];
  const float* Wk = (const float*)d_in[3];
  const float* bk = (const float*)d_in[4];
  const float* Wv = (const float*)d_in[5];
  const float* bv = (const float*)d_in[6];
  const float* Wo = (const float*)d_in[7];
  const float* bo = (const float*)d_in[8];
  float* out = (float*)d_out;

  char* ws = (char*)d_ws;
  ushort_t* xb    = (ushort_t*)ws;  ws += (size_t)NTOK * EMBED * 2;
  ushort_t* wqkvt = (ushort_t*)ws;  ws += (size_t)3 * EMBED * EMBED * 2;
  ushort_t* wot   = (ushort_t*)ws;  ws += (size_t)EMBED * EMBED * 2;
  ushort_t* qb    = (ushort_t*)ws;  ws += (size_t)NTOK * EMBED * 2;
  ushort_t* kb2   = (ushort_t*)ws;  ws += (size_t)NTOK * EMBED * 2;
  ushort_t* vtb   = (ushort_t*)ws;  ws += (size_t)NHEAD * HD * VSTRIDE * 2;
  ushort_t* ao    = (ushort_t*)ws;  ws += (size_t)NTOK * EMBED * 2;
  ushort_t* vb    = ao;   // alias: vb lifetime (gemm0 -> transpose_v) disjoint from ao (flash -> gemm1)

  cvt_x_kernel<<<(NTOK * EMBED) / (256 * 8), 256, 0, stream>>>(x, xb);
  transpose_w4_kernel<<<dim3(24, 24, 4), dim3(32, 8), 0, stream>>>(
      Wq, Wk, Wv, Wo,
      wqkvt, wqkvt + (size_t)EMBED * EMBED, wqkvt + (size_t)2 * EMBED * EMBED, wot);

  gemm_bt_kernel<0><<<dim3(2304 / 128, NTOK / 128), 256, 0, stream>>>(
      xb, wqkvt, bq, bk, bv, qb, kb2, vb, nullptr);

  transpose_v_kernel<<<dim3(2, 128, NHEAD), dim3(32, 8), 0, stream>>>(vb, vtb);

  flash_kernel<<<dim3(NTOK / 64 * NHEAD), 256, 0, stream>>>(qb, kb2, vtb, ao);

  gemm_bt_kernel<1><<<dim3(EMBED / 128, NTOK / 128), 256, 0, stream>>>(
      ao, wot, bo, nullptr, nullptr, nullptr, nullptr, nullptr, out);
}